// Round 11
// baseline (798.637 us; speedup 1.0000x reference)
//
#include <hip/hip_runtime.h>

#define N_TOK 4096
#define DM 256
#define NH 8
#define DK 32

using u16 = unsigned short;
using u32 = unsigned int;
using i64 = long long;
typedef float f32x4 __attribute__((ext_vector_type(4)));

__device__ __forceinline__ float bf2f(u16 u){ return __uint_as_float(((u32)u) << 16); }
__device__ __forceinline__ u16 f2bf(float f){
    u32 x = __float_as_uint(f);
    x += 0x7fffu + ((x >> 16) & 1u);
    return (u16)(x >> 16);
}

// ===== wt_kernel: transpose W[256][256] -> WTb4[d4*256 + c] = {W[c][4d4..4d4+3]}
// Blocks 0..63: 4 matrices x 16 blocks. Blocks 64..79: segment bounds.
__global__ __launch_bounds__(256)
void wt_kernel(const float* __restrict__ Wq, const float* __restrict__ Wk,
               const float* __restrict__ Wv, const float* __restrict__ Wo,
               float* __restrict__ Tq, float* __restrict__ Tk,
               float* __restrict__ Tv, float* __restrict__ To,
               const void* __restrict__ batch_q, const void* __restrict__ batch_kv,
               int2* __restrict__ bounds)
{
    const int b = blockIdx.x;
    const int t = threadIdx.x;
    if (b < 64){
        const float* W = (b < 16) ? Wq : (b < 32) ? Wk : (b < 48) ? Wv : Wo;
        float*      T  = (b < 16) ? Tq : (b < 32) ? Tk : (b < 48) ? Tv : To;
        int blk = b & 15;
        float4* T4 = (float4*)T;
#pragma unroll
        for (int f = 0; f < 4; ++f){
            int F = blk * 1024 + f * 256 + t;
            int d4 = F >> 8;
            int c  = F & 255;
            float4 v = *(const float4*)(W + (size_t)c * DM + 4 * d4);
            T4[F] = v;
        }
    } else {
        int q = (b - 64) * 256 + t;
        const int* kv32 = (const int*)batch_kv;
        const i64* kv64 = (const i64*)batch_kv;
        bool is64 = (kv32[N_TOK - 1] == 0);
        int s = is64 ? (int)((const i64*)batch_q)[q] : ((const int*)batch_q)[q];
        int lo = 0, hi = N_TOK;
        while (lo < hi){ int m = (lo + hi) >> 1; int v = is64 ? (int)kv64[m] : kv32[m]; if (v < s) lo = m + 1; else hi = m; }
        int lo2 = lo, hi2 = N_TOK;
        while (lo2 < hi2){ int m = (lo2 + hi2) >> 1; int v = is64 ? (int)kv64[m] : kv32[m]; if (v <= s) lo2 = m + 1; else hi2 = m; }
        bounds[q] = make_int2(lo, lo2);
    }
}

// ================= fused pre-kernel: projQ (b<1024) | projKV (b<2048) =================
// ROWS=4, x staged in LDS, 2-deep W prefetch (R9 version).
__global__ __launch_bounds__(256)
void pre_kernel(const float* __restrict__ xq, const float* __restrict__ xkv,
                const float* __restrict__ Tq, const float* __restrict__ bq,
                const float* __restrict__ Tk, const float* __restrict__ bk,
                const float* __restrict__ Tv, const float* __restrict__ bv,
                float* __restrict__ Q, u16* __restrict__ Kp, u16* __restrict__ Vp)
{
    __shared__ float4 xs[4][64];   // 4 rows x 1KB
    const int b = blockIdx.x;
    const int c = threadIdx.x;
    const int ROWS = 4;

    if (b < 1024){
        int row0 = b * ROWS;
        xs[c >> 6][c & 63] = ((const float4*)(xq + (size_t)row0 * DM))[c];
        __syncthreads();
        float acc[ROWS];
        float bvv = bq[c];
#pragma unroll
        for (int r = 0; r < ROWS; ++r) acc[r] = bvv;
        const float4* T4 = (const float4*)Tq;
        float4 w = T4[c];
        for (int i = 0; i < 63; ++i){
            float4 wn = T4[(i + 1) * 256 + c];   // prefetch next W slab
#pragma unroll
            for (int r = 0; r < ROWS; ++r){
                float4 xv = xs[r][i];
                acc[r] += xv.x * w.x + xv.y * w.y + xv.z * w.z + xv.w * w.w;
            }
            w = wn;
        }
#pragma unroll
        for (int r = 0; r < ROWS; ++r){
            float4 xv = xs[r][63];
            acc[r] += xv.x * w.x + xv.y * w.y + xv.z * w.z + xv.w * w.w;
        }
#pragma unroll
        for (int r = 0; r < ROWS; ++r)
            Q[(size_t)(row0 + r) * DM + c] = acc[r];
    } else {
        int row0 = (b - 1024) * ROWS;
        xs[c >> 6][c & 63] = ((const float4*)(xkv + (size_t)row0 * DM))[c];
        __syncthreads();
        int hh = c >> 5, dd = c & 31;
        float acck[ROWS], accv[ROWS];
        float bkv = bk[c], bvv = bv[c];
#pragma unroll
        for (int r = 0; r < ROWS; ++r){ acck[r] = bkv; accv[r] = bvv; }
        const float4* Tk4 = (const float4*)Tk;
        const float4* Tv4 = (const float4*)Tv;
        float4 wk = Tk4[c];
        float4 wv = Tv4[c];
        for (int i = 0; i < 63; ++i){
            float4 wkn = Tk4[(i + 1) * 256 + c];
            float4 wvn = Tv4[(i + 1) * 256 + c];
#pragma unroll
            for (int r = 0; r < ROWS; ++r){
                float4 xv = xs[r][i];
                acck[r] += xv.x * wk.x + xv.y * wk.y + xv.z * wk.z + xv.w * wk.w;
                accv[r] += xv.x * wv.x + xv.y * wv.y + xv.z * wv.z + xv.w * wv.w;
            }
            wk = wkn; wv = wvn;
        }
#pragma unroll
        for (int r = 0; r < ROWS; ++r){
            float4 xv = xs[r][63];
            acck[r] += xv.x * wk.x + xv.y * wk.y + xv.z * wk.z + xv.w * wk.w;
            accv[r] += xv.x * wv.x + xv.y * wv.y + xv.z * wv.z + xv.w * wv.w;
        }
#pragma unroll
        for (int r = 0; r < ROWS; ++r){
            size_t idx = ((size_t)hh * N_TOK + (row0 + r)) * DK + dd;
            Kp[idx] = f2bf(acck[r]);
            Vp[idx] = f2bf(accv[r]);
        }
    }
}

// out[r][c] = sum_d x[r][d] * W[c][d] + b[c]  — ROWS=4, LDS-staged x, prefetched W
__global__ __launch_bounds__(256)
void proj_kernel(const float* __restrict__ x, const float* __restrict__ T,
                 const float* __restrict__ bias, float* __restrict__ out)
{
    __shared__ float4 xs[4][64];
    const int ROWS = 4;
    int row0 = blockIdx.x * ROWS;
    int c = threadIdx.x;
    xs[c >> 6][c & 63] = ((const float4*)(x + (size_t)row0 * DM))[c];
    __syncthreads();
    float acc[ROWS];
    float bv = bias[c];
#pragma unroll
    for (int r = 0; r < ROWS; ++r) acc[r] = bv;
    const float4* T4 = (const float4*)T;
    float4 w = T4[c];
    for (int i = 0; i < 63; ++i){
        float4 wn = T4[(i + 1) * 256 + c];
#pragma unroll
        for (int r = 0; r < ROWS; ++r){
            float4 xv = xs[r][i];
            acc[r] += xv.x * w.x + xv.y * w.y + xv.z * w.z + xv.w * w.w;
        }
        w = wn;
    }
#pragma unroll
    for (int r = 0; r < ROWS; ++r){
        float4 xv = xs[r][63];
        acc[r] += xv.x * w.x + xv.y * w.y + xv.z * w.z + xv.w * w.w;
    }
#pragma unroll
    for (int r = 0; r < ROWS; ++r)
        out[(size_t)(row0 + r) * DM + c] = acc[r];
}

// R5 attn chassis, byte-for-byte (measured ~156us standalone in R8).
__global__ __launch_bounds__(256)
void attn_kernel(const float* __restrict__ Q, const u16* __restrict__ K,
                 const u16* __restrict__ V, const int2* __restrict__ bounds,
                 float* __restrict__ attn, float* __restrict__ O)
{
    __shared__ float sc[N_TOK];    // unnormalized probs
    __shared__ float qs[DK];
    __shared__ float red[8];
    __shared__ float Osh[DK];

    int q = blockIdx.x, h = blockIdx.y, tid = threadIdx.x;
    int2 bnd = bounds[q];
    const int lo = bnd.x, hi = bnd.y;
    const u16* Kh = K + (size_t)h * N_TOK * DK;
    const u16* Vh = V + (size_t)h * N_TOK * DK;

    if (tid < DK){ qs[tid] = Q[(size_t)q * DM + h * DK + tid]; Osh[tid] = 0.f; }
    __syncthreads();

    const float scale = 0.17677669529663687f;   // 1/sqrt(32)

    // ---- scores + local max ----
    float lmax = -1e30f;
    for (int k = lo + tid; k < hi; k += 256){
        const uint4* kr = (const uint4*)(Kh + (size_t)k * DK);   // 64B dense
        float dot = 0.f;
#pragma unroll
        for (int i = 0; i < 4; ++i){
            uint4 p = kr[i];
            dot += qs[i*8+0]*bf2f((u16)p.x) + qs[i*8+1]*bf2f((u16)(p.x>>16));
            dot += qs[i*8+2]*bf2f((u16)p.y) + qs[i*8+3]*bf2f((u16)(p.y>>16));
            dot += qs[i*8+4]*bf2f((u16)p.z) + qs[i*8+5]*bf2f((u16)(p.z>>16));
            dot += qs[i*8+6]*bf2f((u16)p.w) + qs[i*8+7]*bf2f((u16)(p.w>>16));
        }
        dot *= scale;
        sc[k - lo] = dot;
        lmax = fmaxf(lmax, dot);
    }
#pragma unroll
    for (int off = 32; off; off >>= 1) lmax = fmaxf(lmax, __shfl_xor(lmax, off, 64));
    if ((tid & 63) == 0) red[tid >> 6] = lmax;
    __syncthreads();
    float m = fmaxf(fmaxf(red[0], red[1]), fmaxf(red[2], red[3]));

    // ---- exp + local sum ----
    float lsum = 0.f;
    for (int k = lo + tid; k < hi; k += 256){
        float p = __expf(sc[k - lo] - m);
        sc[k - lo] = p;
        lsum += p;
    }
#pragma unroll
    for (int off = 32; off; off >>= 1) lsum += __shfl_xor(lsum, off, 64);
    if ((tid & 63) == 0) red[4 + (tid >> 6)] = lsum;
    __syncthreads();
    float sum = red[4] + red[5] + red[6] + red[7];
    float inv = (sum > 0.f) ? (1.0f / sum) : 0.f;

    // ---- full attn row first (stores issue, drain overlaps PV below) ----
    f32x4* arow4 = (f32x4*)(attn + ((size_t)h * N_TOK + q) * N_TOK);
#pragma unroll
    for (int i = 0; i < N_TOK / 1024; ++i){
        int t = i * 256 + tid;
        int k0 = 4 * t;
        f32x4 w;
        w.x = (k0 + 0 >= lo && k0 + 0 < hi) ? sc[k0 + 0 - lo] * inv : 0.f;
        w.y = (k0 + 1 >= lo && k0 + 1 < hi) ? sc[k0 + 1 - lo] * inv : 0.f;
        w.z = (k0 + 2 >= lo && k0 + 2 < hi) ? sc[k0 + 2 - lo] * inv : 0.f;
        w.w = (k0 + 3 >= lo && k0 + 3 < hi) ? sc[k0 + 3 - lo] * inv : 0.f;
        __builtin_nontemporal_store(w, &arow4[t]);
    }

    // ---- PV ----
    int d2 = tid & 15;
    int g  = tid >> 4;
    float p0 = 0.f, p1 = 0.f;
    for (int k = lo + g; k < hi; k += 16){
        u32 pv = *(const u32*)(Vh + (size_t)k * DK + 2 * d2);    // dense 64B/k
        float p = sc[k - lo];
        p0 += p * bf2f((u16)pv);
        p1 += p * bf2f((u16)(pv >> 16));
    }
    p0 += __shfl_xor(p0, 16, 64); p0 += __shfl_xor(p0, 32, 64);
    p1 += __shfl_xor(p1, 16, 64); p1 += __shfl_xor(p1, 32, 64);
    if ((tid & 63) < 16){
        atomicAdd(&Osh[2 * d2 + 0], p0);
        atomicAdd(&Osh[2 * d2 + 1], p1);
    }

    __syncthreads();
    if (tid < DK) O[(size_t)q * DM + h * DK + tid] = Osh[tid] * inv;
}

extern "C" void kernel_launch(void* const* d_in, const int* in_sizes, int n_in,
                              void* d_out, int out_size, void* d_ws, size_t ws_size,
                              hipStream_t stream)
{
    const float* x_q  = (const float*)d_in[0];
    const float* x_kv = (const float*)d_in[1];
    const void* batch_q  = d_in[2];
    const void* batch_kv = d_in[3];
    const float* Wq = (const float*)d_in[4];
    const float* bq = (const float*)d_in[5];
    const float* Wk = (const float*)d_in[6];
    const float* bk = (const float*)d_in[7];
    const float* Wv = (const float*)d_in[8];
    const float* bv = (const float*)d_in[9];
    const float* Wo = (const float*)d_in[10];
    const float* bo = (const float*)d_in[11];

    char* ws = (char*)d_ws;
    float* Q  = (float*)ws;                                 // 4 MB fp32
    u16*   Kp = (u16*)(ws + (size_t)4 * 1024 * 1024);       // 2 MB bf16, head-major
    u16*   Vp = (u16*)(ws + (size_t)6 * 1024 * 1024);       // 2 MB bf16, head-major
    float* O  = (float*)(ws + (size_t)8 * 1024 * 1024);     // 4 MB fp32
    int2* bounds = (int2*)(ws + (size_t)12 * 1024 * 1024);  // 32 KB
    float* Tq = (float*)(ws + (size_t)13 * 1024 * 1024);    // 256 KB each
    float* Tk = (float*)(ws + (size_t)13 * 1024 * 1024 + 256 * 1024);
    float* Tv = (float*)(ws + (size_t)13 * 1024 * 1024 + 512 * 1024);
    float* To = (float*)(ws + (size_t)13 * 1024 * 1024 + 768 * 1024);

    float* out  = (float*)d_out;                            // [4096,256] fp32
    float* attn = out + (size_t)N_TOK * DM;                 // [8,4096,4096] fp32

    // DIAGNOSTIC (resubmitted after infra flake): wt/pre/proj each launched 3x
    // (all idempotent). dur - 670.5 = 2 x projfamily_cost. attn byte-identical.
    wt_kernel<<<80, 256, 0, stream>>>(Wq, Wk, Wv, Wo, Tq, Tk, Tv, To,
                                      batch_q, batch_kv, bounds);
    wt_kernel<<<80, 256, 0, stream>>>(Wq, Wk, Wv, Wo, Tq, Tk, Tv, To,
                                      batch_q, batch_kv, bounds);
    wt_kernel<<<80, 256, 0, stream>>>(Wq, Wk, Wv, Wo, Tq, Tk, Tv, To,
                                      batch_q, batch_kv, bounds);
    pre_kernel<<<2048, 256, 0, stream>>>(x_q, x_kv, Tq, bq, Tk, bk, Tv, bv,
                                         Q, Kp, Vp);
    pre_kernel<<<2048, 256, 0, stream>>>(x_q, x_kv, Tq, bq, Tk, bk, Tv, bv,
                                         Q, Kp, Vp);
    pre_kernel<<<2048, 256, 0, stream>>>(x_q, x_kv, Tq, bq, Tk, bk, Tv, bv,
                                         Q, Kp, Vp);
    attn_kernel<<<dim3(N_TOK, NH), 256, 0, stream>>>(Q, Kp, Vp, bounds, attn, O);
    proj_kernel<<<N_TOK/4, 256, 0, stream>>>((const float*)O, To, bo, out);
    proj_kernel<<<N_TOK/4, 256, 0, stream>>>((const float*)O, To, bo, out);
    proj_kernel<<<N_TOK/4, 256, 0, stream>>>((const float*)O, To, bo, out);
}

// Round 12
// 654.276 us; speedup vs baseline: 1.2206x; 1.2206x over previous
//
#include <hip/hip_runtime.h>

#define N_TOK 4096
#define DM 256
#define NH 8
#define DK 32

using u16 = unsigned short;
using u32 = unsigned int;
using i64 = long long;
typedef float f32x4 __attribute__((ext_vector_type(4)));

__device__ __forceinline__ float bf2f(u16 u){ return __uint_as_float(((u32)u) << 16); }
__device__ __forceinline__ u16 f2bf(float f){
    u32 x = __float_as_uint(f);
    x += 0x7fffu + ((x >> 16) & 1u);
    return (u16)(x >> 16);
}

// ===== wt_kernel: transpose W[256][256] -> WTb4[d4*256 + c] = {W[c][4d4..4d4+3]}
// Blocks 0..63: 4 matrices x 16 blocks. Blocks 64..79: segment bounds.
__global__ __launch_bounds__(256)
void wt_kernel(const float* __restrict__ Wq, const float* __restrict__ Wk,
               const float* __restrict__ Wv, const float* __restrict__ Wo,
               float* __restrict__ Tq, float* __restrict__ Tk,
               float* __restrict__ Tv, float* __restrict__ To,
               const void* __restrict__ batch_q, const void* __restrict__ batch_kv,
               int2* __restrict__ bounds)
{
    const int b = blockIdx.x;
    const int t = threadIdx.x;
    if (b < 64){
        const float* W = (b < 16) ? Wq : (b < 32) ? Wk : (b < 48) ? Wv : Wo;
        float*      T  = (b < 16) ? Tq : (b < 32) ? Tk : (b < 48) ? Tv : To;
        int blk = b & 15;
        float4* T4 = (float4*)T;
#pragma unroll
        for (int f = 0; f < 4; ++f){
            int F = blk * 1024 + f * 256 + t;
            int d4 = F >> 8;
            int c  = F & 255;
            float4 v = *(const float4*)(W + (size_t)c * DM + 4 * d4);
            T4[F] = v;
        }
    } else {
        int q = (b - 64) * 256 + t;
        const int* kv32 = (const int*)batch_kv;
        const i64* kv64 = (const i64*)batch_kv;
        bool is64 = (kv32[N_TOK - 1] == 0);
        int s = is64 ? (int)((const i64*)batch_q)[q] : ((const int*)batch_q)[q];
        int lo = 0, hi = N_TOK;
        while (lo < hi){ int m = (lo + hi) >> 1; int v = is64 ? (int)kv64[m] : kv32[m]; if (v < s) lo = m + 1; else hi = m; }
        int lo2 = lo, hi2 = N_TOK;
        while (lo2 < hi2){ int m = (lo2 + hi2) >> 1; int v = is64 ? (int)kv64[m] : kv32[m]; if (v <= s) lo2 = m + 1; else hi2 = m; }
        bounds[q] = make_int2(lo, lo2);
    }
}

// ================= fused pre-kernel: projQ (b<1024) | projKV (b<2048) =================
// ROWS=4, x staged in LDS, 2-deep W prefetch (R9 version).
__global__ __launch_bounds__(256)
void pre_kernel(const float* __restrict__ xq, const float* __restrict__ xkv,
                const float* __restrict__ Tq, const float* __restrict__ bq,
                const float* __restrict__ Tk, const float* __restrict__ bk,
                const float* __restrict__ Tv, const float* __restrict__ bv,
                float* __restrict__ Q, u16* __restrict__ Kp, u16* __restrict__ Vp)
{
    __shared__ float4 xs[4][64];   // 4 rows x 1KB
    const int b = blockIdx.x;
    const int c = threadIdx.x;
    const int ROWS = 4;

    if (b < 1024){
        int row0 = b * ROWS;
        xs[c >> 6][c & 63] = ((const float4*)(xq + (size_t)row0 * DM))[c];
        __syncthreads();
        float acc[ROWS];
        float bvv = bq[c];
#pragma unroll
        for (int r = 0; r < ROWS; ++r) acc[r] = bvv;
        const float4* T4 = (const float4*)Tq;
        float4 w = T4[c];
        for (int i = 0; i < 63; ++i){
            float4 wn = T4[(i + 1) * 256 + c];   // prefetch next W slab
#pragma unroll
            for (int r = 0; r < ROWS; ++r){
                float4 xv = xs[r][i];
                acc[r] += xv.x * w.x + xv.y * w.y + xv.z * w.z + xv.w * w.w;
            }
            w = wn;
        }
#pragma unroll
        for (int r = 0; r < ROWS; ++r){
            float4 xv = xs[r][63];
            acc[r] += xv.x * w.x + xv.y * w.y + xv.z * w.z + xv.w * w.w;
        }
#pragma unroll
        for (int r = 0; r < ROWS; ++r)
            Q[(size_t)(row0 + r) * DM + c] = acc[r];
    } else {
        int row0 = (b - 1024) * ROWS;
        xs[c >> 6][c & 63] = ((const float4*)(xkv + (size_t)row0 * DM))[c];
        __syncthreads();
        int hh = c >> 5, dd = c & 31;
        float acck[ROWS], accv[ROWS];
        float bkv = bk[c], bvv = bv[c];
#pragma unroll
        for (int r = 0; r < ROWS; ++r){ acck[r] = bkv; accv[r] = bvv; }
        const float4* Tk4 = (const float4*)Tk;
        const float4* Tv4 = (const float4*)Tv;
        float4 wk = Tk4[c];
        float4 wv = Tv4[c];
        for (int i = 0; i < 63; ++i){
            float4 wkn = Tk4[(i + 1) * 256 + c];
            float4 wvn = Tv4[(i + 1) * 256 + c];
#pragma unroll
            for (int r = 0; r < ROWS; ++r){
                float4 xv = xs[r][i];
                acck[r] += xv.x * wk.x + xv.y * wk.y + xv.z * wk.z + xv.w * wk.w;
                accv[r] += xv.x * wv.x + xv.y * wv.y + xv.z * wv.z + xv.w * wv.w;
            }
            wk = wkn; wv = wvn;
        }
#pragma unroll
        for (int r = 0; r < ROWS; ++r){
            float4 xv = xs[r][63];
            acck[r] += xv.x * wk.x + xv.y * wk.y + xv.z * wk.z + xv.w * wk.w;
            accv[r] += xv.x * wv.x + xv.y * wv.y + xv.z * wv.z + xv.w * wv.w;
        }
#pragma unroll
        for (int r = 0; r < ROWS; ++r){
            size_t idx = ((size_t)hh * N_TOK + (row0 + r)) * DK + dd;
            Kp[idx] = f2bf(acck[r]);
            Vp[idx] = f2bf(accv[r]);
        }
    }
}

// out[r][c] = sum_d x[r][d] * W[c][d] + b[c]  — ROWS=4, LDS-staged x, prefetched W
__global__ __launch_bounds__(256)
void proj_kernel(const float* __restrict__ x, const float* __restrict__ T,
                 const float* __restrict__ bias, float* __restrict__ out)
{
    __shared__ float4 xs[4][64];
    const int ROWS = 4;
    int row0 = blockIdx.x * ROWS;
    int c = threadIdx.x;
    xs[c >> 6][c & 63] = ((const float4*)(x + (size_t)row0 * DM))[c];
    __syncthreads();
    float acc[ROWS];
    float bv = bias[c];
#pragma unroll
    for (int r = 0; r < ROWS; ++r) acc[r] = bv;
    const float4* T4 = (const float4*)T;
    float4 w = T4[c];
    for (int i = 0; i < 63; ++i){
        float4 wn = T4[(i + 1) * 256 + c];
#pragma unroll
        for (int r = 0; r < ROWS; ++r){
            float4 xv = xs[r][i];
            acc[r] += xv.x * w.x + xv.y * w.y + xv.z * w.z + xv.w * w.w;
        }
        w = wn;
    }
#pragma unroll
    for (int r = 0; r < ROWS; ++r){
        float4 xv = xs[r][63];
        acc[r] += xv.x * w.x + xv.y * w.y + xv.z * w.z + xv.w * w.w;
    }
#pragma unroll
    for (int r = 0; r < ROWS; ++r)
        out[(size_t)(row0 + r) * DM + c] = acc[r];
}

// R5 attn chassis + PHASE STAGGER: blocks with (q^h)&1 run {PV, stores},
// others {stores, PV}. Both orders are valid (each phase only reads sc[]
// after the sum barrier; phases touch disjoint memory). At any instant
// ~half the resident blocks are storing -> NT-write stream stays occupied
// instead of chip-wide phase-locked bursts.
__global__ __launch_bounds__(256)
void attn_kernel(const float* __restrict__ Q, const u16* __restrict__ K,
                 const u16* __restrict__ V, const int2* __restrict__ bounds,
                 float* __restrict__ attn, float* __restrict__ O)
{
    __shared__ float sc[N_TOK];    // unnormalized probs
    __shared__ float qs[DK];
    __shared__ float red[8];
    __shared__ float Osh[DK];

    int q = blockIdx.x, h = blockIdx.y, tid = threadIdx.x;
    int2 bnd = bounds[q];
    const int lo = bnd.x, hi = bnd.y;
    const u16* Kh = K + (size_t)h * N_TOK * DK;
    const u16* Vh = V + (size_t)h * N_TOK * DK;

    if (tid < DK){ qs[tid] = Q[(size_t)q * DM + h * DK + tid]; Osh[tid] = 0.f; }
    __syncthreads();

    const float scale = 0.17677669529663687f;   // 1/sqrt(32)

    // ---- scores + local max ----
    float lmax = -1e30f;
    for (int k = lo + tid; k < hi; k += 256){
        const uint4* kr = (const uint4*)(Kh + (size_t)k * DK);   // 64B dense
        float dot = 0.f;
#pragma unroll
        for (int i = 0; i < 4; ++i){
            uint4 p = kr[i];
            dot += qs[i*8+0]*bf2f((u16)p.x) + qs[i*8+1]*bf2f((u16)(p.x>>16));
            dot += qs[i*8+2]*bf2f((u16)p.y) + qs[i*8+3]*bf2f((u16)(p.y>>16));
            dot += qs[i*8+4]*bf2f((u16)p.z) + qs[i*8+5]*bf2f((u16)(p.z>>16));
            dot += qs[i*8+6]*bf2f((u16)p.w) + qs[i*8+7]*bf2f((u16)(p.w>>16));
        }
        dot *= scale;
        sc[k - lo] = dot;
        lmax = fmaxf(lmax, dot);
    }
#pragma unroll
    for (int off = 32; off; off >>= 1) lmax = fmaxf(lmax, __shfl_xor(lmax, off, 64));
    if ((tid & 63) == 0) red[tid >> 6] = lmax;
    __syncthreads();
    float m = fmaxf(fmaxf(red[0], red[1]), fmaxf(red[2], red[3]));

    // ---- exp + local sum ----
    float lsum = 0.f;
    for (int k = lo + tid; k < hi; k += 256){
        float p = __expf(sc[k - lo] - m);
        sc[k - lo] = p;
        lsum += p;
    }
#pragma unroll
    for (int off = 32; off; off >>= 1) lsum += __shfl_xor(lsum, off, 64);
    if ((tid & 63) == 0) red[4 + (tid >> 6)] = lsum;
    __syncthreads();
    float sum = red[4] + red[5] + red[6] + red[7];
    float inv = (sum > 0.f) ? (1.0f / sum) : 0.f;

    const int swap = (q ^ h) & 1;   // phase stagger

    f32x4* arow4 = (f32x4*)(attn + ((size_t)h * N_TOK + q) * N_TOK);
    float p0 = 0.f, p1 = 0.f;
    int d2 = tid & 15;
    int g  = tid >> 4;

    if (!swap){
        // ---- stores, then PV ----
#pragma unroll
        for (int i = 0; i < N_TOK / 1024; ++i){
            int t = i * 256 + tid;
            int k0 = 4 * t;
            f32x4 w;
            w.x = (k0 + 0 >= lo && k0 + 0 < hi) ? sc[k0 + 0 - lo] * inv : 0.f;
            w.y = (k0 + 1 >= lo && k0 + 1 < hi) ? sc[k0 + 1 - lo] * inv : 0.f;
            w.z = (k0 + 2 >= lo && k0 + 2 < hi) ? sc[k0 + 2 - lo] * inv : 0.f;
            w.w = (k0 + 3 >= lo && k0 + 3 < hi) ? sc[k0 + 3 - lo] * inv : 0.f;
            __builtin_nontemporal_store(w, &arow4[t]);
        }
        for (int k = lo + g; k < hi; k += 16){
            u32 pv = *(const u32*)(Vh + (size_t)k * DK + 2 * d2);
            float p = sc[k - lo];
            p0 += p * bf2f((u16)pv);
            p1 += p * bf2f((u16)(pv >> 16));
        }
    } else {
        // ---- PV, then stores ----
        for (int k = lo + g; k < hi; k += 16){
            u32 pv = *(const u32*)(Vh + (size_t)k * DK + 2 * d2);
            float p = sc[k - lo];
            p0 += p * bf2f((u16)pv);
            p1 += p * bf2f((u16)(pv >> 16));
        }
#pragma unroll
        for (int i = 0; i < N_TOK / 1024; ++i){
            int t = i * 256 + tid;
            int k0 = 4 * t;
            f32x4 w;
            w.x = (k0 + 0 >= lo && k0 + 0 < hi) ? sc[k0 + 0 - lo] * inv : 0.f;
            w.y = (k0 + 1 >= lo && k0 + 1 < hi) ? sc[k0 + 1 - lo] * inv : 0.f;
            w.z = (k0 + 2 >= lo && k0 + 2 < hi) ? sc[k0 + 2 - lo] * inv : 0.f;
            w.w = (k0 + 3 >= lo && k0 + 3 < hi) ? sc[k0 + 3 - lo] * inv : 0.f;
            __builtin_nontemporal_store(w, &arow4[t]);
        }
    }

    p0 += __shfl_xor(p0, 16, 64); p0 += __shfl_xor(p0, 32, 64);
    p1 += __shfl_xor(p1, 16, 64); p1 += __shfl_xor(p1, 32, 64);
    if ((tid & 63) < 16){
        atomicAdd(&Osh[2 * d2 + 0], p0);
        atomicAdd(&Osh[2 * d2 + 1], p1);
    }

    __syncthreads();
    if (tid < DK) O[(size_t)q * DM + h * DK + tid] = Osh[tid] * inv;
}

extern "C" void kernel_launch(void* const* d_in, const int* in_sizes, int n_in,
                              void* d_out, int out_size, void* d_ws, size_t ws_size,
                              hipStream_t stream)
{
    const float* x_q  = (const float*)d_in[0];
    const float* x_kv = (const float*)d_in[1];
    const void* batch_q  = d_in[2];
    const void* batch_kv = d_in[3];
    const float* Wq = (const float*)d_in[4];
    const float* bq = (const float*)d_in[5];
    const float* Wk = (const float*)d_in[6];
    const float* bk = (const float*)d_in[7];
    const float* Wv = (const float*)d_in[8];
    const float* bv = (const float*)d_in[9];
    const float* Wo = (const float*)d_in[10];
    const float* bo = (const float*)d_in[11];

    char* ws = (char*)d_ws;
    float* Q  = (float*)ws;                                 // 4 MB fp32
    u16*   Kp = (u16*)(ws + (size_t)4 * 1024 * 1024);       // 2 MB bf16, head-major
    u16*   Vp = (u16*)(ws + (size_t)6 * 1024 * 1024);       // 2 MB bf16, head-major
    float* O  = (float*)(ws + (size_t)8 * 1024 * 1024);     // 4 MB fp32
    int2* bounds = (int2*)(ws + (size_t)12 * 1024 * 1024);  // 32 KB
    float* Tq = (float*)(ws + (size_t)13 * 1024 * 1024);    // 256 KB each
    float* Tk = (float*)(ws + (size_t)13 * 1024 * 1024 + 256 * 1024);
    float* Tv = (float*)(ws + (size_t)13 * 1024 * 1024 + 512 * 1024);
    float* To = (float*)(ws + (size_t)13 * 1024 * 1024 + 768 * 1024);

    float* out  = (float*)d_out;                            // [4096,256] fp32
    float* attn = out + (size_t)N_TOK * DM;                 // [8,4096,4096] fp32

    wt_kernel<<<80, 256, 0, stream>>>(Wq, Wk, Wv, Wo, Tq, Tk, Tv, To,
                                      batch_q, batch_kv, bounds);
    pre_kernel<<<2048, 256, 0, stream>>>(x_q, x_kv, Tq, bq, Tk, bk, Tv, bv,
                                         Q, Kp, Vp);
    attn_kernel<<<dim3(N_TOK, NH), 256, 0, stream>>>(Q, Kp, Vp, bounds, attn, O);
    proj_kernel<<<N_TOK/4, 256, 0, stream>>>((const float*)O, To, bo, out);
}

// Round 13
// 654.087 us; speedup vs baseline: 1.2210x; 1.0003x over previous
//
#include <hip/hip_runtime.h>

#define N_TOK 4096
#define DM 256
#define NH 8
#define DK 32

using u16 = unsigned short;
using u32 = unsigned int;
using i64 = long long;
typedef float f32x4 __attribute__((ext_vector_type(4)));

__device__ __forceinline__ float bf2f(u16 u){ return __uint_as_float(((u32)u) << 16); }
__device__ __forceinline__ u16 f2bf(float f){
    u32 x = __float_as_uint(f);
    x += 0x7fffu + ((x >> 16) & 1u);
    return (u16)(x >> 16);
}

// ===== wt_kernel: transpose W[256][256] -> WTb4[d4*256 + c] = {W[c][4d4..4d4+3]}
// Blocks 0..63: 4 matrices x 16 blocks. Blocks 64..79: segment bounds.
__global__ __launch_bounds__(256)
void wt_kernel(const float* __restrict__ Wq, const float* __restrict__ Wk,
               const float* __restrict__ Wv, const float* __restrict__ Wo,
               float* __restrict__ Tq, float* __restrict__ Tk,
               float* __restrict__ Tv, float* __restrict__ To,
               const void* __restrict__ batch_q, const void* __restrict__ batch_kv,
               int2* __restrict__ bounds)
{
    const int b = blockIdx.x;
    const int t = threadIdx.x;
    if (b < 64){
        const float* W = (b < 16) ? Wq : (b < 32) ? Wk : (b < 48) ? Wv : Wo;
        float*      T  = (b < 16) ? Tq : (b < 32) ? Tk : (b < 48) ? Tv : To;
        int blk = b & 15;
        float4* T4 = (float4*)T;
#pragma unroll
        for (int f = 0; f < 4; ++f){
            int F = blk * 1024 + f * 256 + t;
            int d4 = F >> 8;
            int c  = F & 255;
            float4 v = *(const float4*)(W + (size_t)c * DM + 4 * d4);
            T4[F] = v;
        }
    } else {
        int q = (b - 64) * 256 + t;
        const int* kv32 = (const int*)batch_kv;
        const i64* kv64 = (const i64*)batch_kv;
        bool is64 = (kv32[N_TOK - 1] == 0);
        int s = is64 ? (int)((const i64*)batch_q)[q] : ((const int*)batch_q)[q];
        int lo = 0, hi = N_TOK;
        while (lo < hi){ int m = (lo + hi) >> 1; int v = is64 ? (int)kv64[m] : kv32[m]; if (v < s) lo = m + 1; else hi = m; }
        int lo2 = lo, hi2 = N_TOK;
        while (lo2 < hi2){ int m = (lo2 + hi2) >> 1; int v = is64 ? (int)kv64[m] : kv32[m]; if (v <= s) lo2 = m + 1; else hi2 = m; }
        bounds[q] = make_int2(lo, lo2);
    }
}

// ================= fused pre-kernel: projQ (b<1024) | projKV (b<2048) =================
// ROWS=4, x staged in LDS, 2-deep W prefetch (R9 version).
__global__ __launch_bounds__(256)
void pre_kernel(const float* __restrict__ xq, const float* __restrict__ xkv,
                const float* __restrict__ Tq, const float* __restrict__ bq,
                const float* __restrict__ Tk, const float* __restrict__ bk,
                const float* __restrict__ Tv, const float* __restrict__ bv,
                float* __restrict__ Q, u16* __restrict__ Kp, u16* __restrict__ Vp)
{
    __shared__ float4 xs[4][64];   // 4 rows x 1KB
    const int b = blockIdx.x;
    const int c = threadIdx.x;
    const int ROWS = 4;

    if (b < 1024){
        int row0 = b * ROWS;
        xs[c >> 6][c & 63] = ((const float4*)(xq + (size_t)row0 * DM))[c];
        __syncthreads();
        float acc[ROWS];
        float bvv = bq[c];
#pragma unroll
        for (int r = 0; r < ROWS; ++r) acc[r] = bvv;
        const float4* T4 = (const float4*)Tq;
        float4 w = T4[c];
        for (int i = 0; i < 63; ++i){
            float4 wn = T4[(i + 1) * 256 + c];   // prefetch next W slab
#pragma unroll
            for (int r = 0; r < ROWS; ++r){
                float4 xv = xs[r][i];
                acc[r] += xv.x * w.x + xv.y * w.y + xv.z * w.z + xv.w * w.w;
            }
            w = wn;
        }
#pragma unroll
        for (int r = 0; r < ROWS; ++r){
            float4 xv = xs[r][63];
            acc[r] += xv.x * w.x + xv.y * w.y + xv.z * w.z + xv.w * w.w;
        }
#pragma unroll
        for (int r = 0; r < ROWS; ++r)
            Q[(size_t)(row0 + r) * DM + c] = acc[r];
    } else {
        int row0 = (b - 1024) * ROWS;
        xs[c >> 6][c & 63] = ((const float4*)(xkv + (size_t)row0 * DM))[c];
        __syncthreads();
        int hh = c >> 5, dd = c & 31;
        float acck[ROWS], accv[ROWS];
        float bkv = bk[c], bvv = bv[c];
#pragma unroll
        for (int r = 0; r < ROWS; ++r){ acck[r] = bkv; accv[r] = bvv; }
        const float4* Tk4 = (const float4*)Tk;
        const float4* Tv4 = (const float4*)Tv;
        float4 wk = Tk4[c];
        float4 wv = Tv4[c];
        for (int i = 0; i < 63; ++i){
            float4 wkn = Tk4[(i + 1) * 256 + c];
            float4 wvn = Tv4[(i + 1) * 256 + c];
#pragma unroll
            for (int r = 0; r < ROWS; ++r){
                float4 xv = xs[r][i];
                acck[r] += xv.x * wk.x + xv.y * wk.y + xv.z * wk.z + xv.w * wk.w;
                accv[r] += xv.x * wv.x + xv.y * wv.y + xv.z * wv.z + xv.w * wv.w;
            }
            wk = wkn; wv = wvn;
        }
#pragma unroll
        for (int r = 0; r < ROWS; ++r){
            float4 xv = xs[r][63];
            acck[r] += xv.x * wk.x + xv.y * wk.y + xv.z * wk.z + xv.w * wk.w;
            accv[r] += xv.x * wv.x + xv.y * wv.y + xv.z * wv.z + xv.w * wv.w;
        }
#pragma unroll
        for (int r = 0; r < ROWS; ++r){
            size_t idx = ((size_t)hh * N_TOK + (row0 + r)) * DK + dd;
            Kp[idx] = f2bf(acck[r]);
            Vp[idx] = f2bf(accv[r]);
        }
    }
}

// out[r][c] = sum_d x[r][d] * W[c][d] + b[c]  — ROWS=4, LDS-staged x, prefetched W
__global__ __launch_bounds__(256)
void proj_kernel(const float* __restrict__ x, const float* __restrict__ T,
                 const float* __restrict__ bias, float* __restrict__ out)
{
    __shared__ float4 xs[4][64];
    const int ROWS = 4;
    int row0 = blockIdx.x * ROWS;
    int c = threadIdx.x;
    xs[c >> 6][c & 63] = ((const float4*)(x + (size_t)row0 * DM))[c];
    __syncthreads();
    float acc[ROWS];
    float bv = bias[c];
#pragma unroll
    for (int r = 0; r < ROWS; ++r) acc[r] = bv;
    const float4* T4 = (const float4*)T;
    float4 w = T4[c];
    for (int i = 0; i < 63; ++i){
        float4 wn = T4[(i + 1) * 256 + c];
#pragma unroll
        for (int r = 0; r < ROWS; ++r){
            float4 xv = xs[r][i];
            acc[r] += xv.x * w.x + xv.y * w.y + xv.z * w.z + xv.w * w.w;
        }
        w = wn;
    }
#pragma unroll
    for (int r = 0; r < ROWS; ++r){
        float4 xv = xs[r][63];
        acc[r] += xv.x * w.x + xv.y * w.y + xv.z * w.z + xv.w * w.w;
    }
#pragma unroll
    for (int r = 0; r < ROWS; ++r)
        out[(size_t)(row0 + r) * DM + c] = acc[r];
}

// R12 chassis + WITHIN-BLOCK store/PV interleave: the tail is one loop of
// 4 rounds, each {1 NT-store chunk, then a quarter of the PV k-range}.
// Every block now emits stores continuously through its tail, independent
// of inter-block phase alignment (R12's parity stagger only got half this).
// chunk is a multiple of 16, so the PV k-sequence (ascending, stride 16,
// offset g) is IDENTICAL to the single-loop version -> bit-identical p0/p1.
__global__ __launch_bounds__(256)
void attn_kernel(const float* __restrict__ Q, const u16* __restrict__ K,
                 const u16* __restrict__ V, const int2* __restrict__ bounds,
                 float* __restrict__ attn, float* __restrict__ O)
{
    __shared__ float sc[N_TOK];    // unnormalized probs
    __shared__ float qs[DK];
    __shared__ float red[8];
    __shared__ float Osh[DK];

    int q = blockIdx.x, h = blockIdx.y, tid = threadIdx.x;
    int2 bnd = bounds[q];
    const int lo = bnd.x, hi = bnd.y;
    const u16* Kh = K + (size_t)h * N_TOK * DK;
    const u16* Vh = V + (size_t)h * N_TOK * DK;

    if (tid < DK){ qs[tid] = Q[(size_t)q * DM + h * DK + tid]; Osh[tid] = 0.f; }
    __syncthreads();

    const float scale = 0.17677669529663687f;   // 1/sqrt(32)

    // ---- scores + local max ----
    float lmax = -1e30f;
    for (int k = lo + tid; k < hi; k += 256){
        const uint4* kr = (const uint4*)(Kh + (size_t)k * DK);   // 64B dense
        float dot = 0.f;
#pragma unroll
        for (int i = 0; i < 4; ++i){
            uint4 p = kr[i];
            dot += qs[i*8+0]*bf2f((u16)p.x) + qs[i*8+1]*bf2f((u16)(p.x>>16));
            dot += qs[i*8+2]*bf2f((u16)p.y) + qs[i*8+3]*bf2f((u16)(p.y>>16));
            dot += qs[i*8+4]*bf2f((u16)p.z) + qs[i*8+5]*bf2f((u16)(p.z>>16));
            dot += qs[i*8+6]*bf2f((u16)p.w) + qs[i*8+7]*bf2f((u16)(p.w>>16));
        }
        dot *= scale;
        sc[k - lo] = dot;
        lmax = fmaxf(lmax, dot);
    }
#pragma unroll
    for (int off = 32; off; off >>= 1) lmax = fmaxf(lmax, __shfl_xor(lmax, off, 64));
    if ((tid & 63) == 0) red[tid >> 6] = lmax;
    __syncthreads();
    float m = fmaxf(fmaxf(red[0], red[1]), fmaxf(red[2], red[3]));

    // ---- exp + local sum ----
    float lsum = 0.f;
    for (int k = lo + tid; k < hi; k += 256){
        float p = __expf(sc[k - lo] - m);
        sc[k - lo] = p;
        lsum += p;
    }
#pragma unroll
    for (int off = 32; off; off >>= 1) lsum += __shfl_xor(lsum, off, 64);
    if ((tid & 63) == 0) red[4 + (tid >> 6)] = lsum;
    __syncthreads();
    float sum = red[4] + red[5] + red[6] + red[7];
    float inv = (sum > 0.f) ? (1.0f / sum) : 0.f;

    // ---- interleaved tail: {store chunk i} + {PV quarter i}, i = 0..3 ----
    f32x4* arow4 = (f32x4*)(attn + ((size_t)h * N_TOK + q) * N_TOK);
    const int d2 = tid & 15;
    const int g  = tid >> 4;
    const int seglen = hi - lo;
    const int chunk = ((seglen + 63) >> 6) << 4;   // mult of 16; 4*chunk >= seglen
    float p0 = 0.f, p1 = 0.f;
#pragma unroll
    for (int i = 0; i < 4; ++i){
        // one NT-store chunk (1/4 of the row)
        int t = i * 256 + tid;
        int k0 = 4 * t;
        f32x4 w;
        w.x = (k0 + 0 >= lo && k0 + 0 < hi) ? sc[k0 + 0 - lo] * inv : 0.f;
        w.y = (k0 + 1 >= lo && k0 + 1 < hi) ? sc[k0 + 1 - lo] * inv : 0.f;
        w.z = (k0 + 2 >= lo && k0 + 2 < hi) ? sc[k0 + 2 - lo] * inv : 0.f;
        w.w = (k0 + 3 >= lo && k0 + 3 < hi) ? sc[k0 + 3 - lo] * inv : 0.f;
        __builtin_nontemporal_store(w, &arow4[t]);
        // one PV quarter (same ascending k order as the unsplit loop)
        int kend = lo + (i + 1) * chunk;
        if (kend > hi) kend = hi;
        for (int k = lo + i * chunk + g; k < kend; k += 16){
            u32 pv = *(const u32*)(Vh + (size_t)k * DK + 2 * d2);
            float p = sc[k - lo];
            p0 += p * bf2f((u16)pv);
            p1 += p * bf2f((u16)(pv >> 16));
        }
    }

    p0 += __shfl_xor(p0, 16, 64); p0 += __shfl_xor(p0, 32, 64);
    p1 += __shfl_xor(p1, 16, 64); p1 += __shfl_xor(p1, 32, 64);
    if ((tid & 63) < 16){
        atomicAdd(&Osh[2 * d2 + 0], p0);
        atomicAdd(&Osh[2 * d2 + 1], p1);
    }

    __syncthreads();
    if (tid < DK) O[(size_t)q * DM + h * DK + tid] = Osh[tid] * inv;
}

extern "C" void kernel_launch(void* const* d_in, const int* in_sizes, int n_in,
                              void* d_out, int out_size, void* d_ws, size_t ws_size,
                              hipStream_t stream)
{
    const float* x_q  = (const float*)d_in[0];
    const float* x_kv = (const float*)d_in[1];
    const void* batch_q  = d_in[2];
    const void* batch_kv = d_in[3];
    const float* Wq = (const float*)d_in[4];
    const float* bq = (const float*)d_in[5];
    const float* Wk = (const float*)d_in[6];
    const float* bk = (const float*)d_in[7];
    const float* Wv = (const float*)d_in[8];
    const float* bv = (const float*)d_in[9];
    const float* Wo = (const float*)d_in[10];
    const float* bo = (const float*)d_in[11];

    char* ws = (char*)d_ws;
    float* Q  = (float*)ws;                                 // 4 MB fp32
    u16*   Kp = (u16*)(ws + (size_t)4 * 1024 * 1024);       // 2 MB bf16, head-major
    u16*   Vp = (u16*)(ws + (size_t)6 * 1024 * 1024);       // 2 MB bf16, head-major
    float* O  = (float*)(ws + (size_t)8 * 1024 * 1024);     // 4 MB fp32
    int2* bounds = (int2*)(ws + (size_t)12 * 1024 * 1024);  // 32 KB
    float* Tq = (float*)(ws + (size_t)13 * 1024 * 1024);    // 256 KB each
    float* Tk = (float*)(ws + (size_t)13 * 1024 * 1024 + 256 * 1024);
    float* Tv = (float*)(ws + (size_t)13 * 1024 * 1024 + 512 * 1024);
    float* To = (float*)(ws + (size_t)13 * 1024 * 1024 + 768 * 1024);

    float* out  = (float*)d_out;                            // [4096,256] fp32
    float* attn = out + (size_t)N_TOK * DM;                 // [8,4096,4096] fp32

    wt_kernel<<<80, 256, 0, stream>>>(Wq, Wk, Wv, Wo, Tq, Tk, Tv, To,
                                      batch_q, batch_kv, bounds);
    pre_kernel<<<2048, 256, 0, stream>>>(x_q, x_kv, Tq, bq, Tk, bk, Tv, bv,
                                         Q, Kp, Vp);
    attn_kernel<<<dim3(N_TOK, NH), 256, 0, stream>>>(Q, Kp, Vp, bounds, attn, O);
    proj_kernel<<<N_TOK/4, 256, 0, stream>>>((const float*)O, To, bo, out);
}